// Round 3
// baseline (857.360 us; speedup 1.0000x reference)
//
#include <hip/hip_runtime.h>
#include <stdint.h>

// Problem constants
#define B_SZ   4
#define T_SEQ  2048
#define C_DIM  1024
#define N_HEAD 16
#define HEAD_D 64
#define SCALE  0.125f   // 1/sqrt(64)

typedef unsigned short u16;
typedef __bf16  bfv8  __attribute__((ext_vector_type(8)));
typedef float   f32x4 __attribute__((ext_vector_type(4)));

__device__ __forceinline__ float bf2f(u16 v) {
  union { unsigned int i; float f; } u; u.i = ((unsigned int)v) << 16; return u.f;
}
__device__ __forceinline__ u16 f2bf(float f) {
  union { float f; unsigned int i; } u; u.f = f;
  unsigned int r = u.i + 0x7FFFu + ((u.i >> 16) & 1u);  // RNE
  return (u16)(r >> 16);
}

// fp32 -> bf16 elementwise (inputs are fp32 per the reference; internal
// compute is bf16 MFMA, allowed by the 2%-relative threshold)
__global__ __launch_bounds__(256) void cvt_kernel(const float* __restrict__ src,
                                                  u16* __restrict__ dst, int n4) {
  int i = blockIdx.x * blockDim.x + threadIdx.x;
  if (i < n4) {
    float4 v = ((const float4*)src)[i];
    ushort4 o;
    o.x = f2bf(v.x); o.y = f2bf(v.y); o.z = f2bf(v.z); o.w = f2bf(v.w);
    ((ushort4*)dst)[i] = o;
  }
}

// ---------------------------------------------------------------------------
// NT GEMM core: C[m,n] = sum_k A[m,k]*Bw[n,k]; A (Mx1024), Bw (Nx1024), bf16.
// 128x128 block tile, BK=32, 4 waves in 2x2, each wave 4x4 of 16x16x32 MFMA.
// Explicit staging: thread t stages row t>>1, cols (t&1)*16..+15 (32B each).
// ---------------------------------------------------------------------------
__device__ __forceinline__ void gemm_core(const u16* __restrict__ A,
                                          const u16* __restrict__ Bw,
                                          int m0, int n0,
                                          f32x4 acc[4][4],
                                          __bf16* As, __bf16* Bs) {
  const int tid  = threadIdx.x;
  const int wave = tid >> 6;
  const int lane = tid & 63;
  const int srow = tid >> 1;         // staging row 0..127
  const int scol = (tid & 1) * 16;   // staging col 0 or 16
  const int frow = lane & 15;        // MFMA A/B frag: m/n = lane&15
  const int fk   = (lane >> 4) * 8;  // k = quad*8 + j
  const int wm   = wave >> 1, wn = wave & 1;

  for (int k0 = 0; k0 < C_DIM; k0 += 32) {
    const u16* ga = A  + (size_t)(m0 + srow) * C_DIM + k0 + scol;
    const u16* gb = Bw + (size_t)(n0 + srow) * C_DIM + k0 + scol;
    int4 a0 = *(const int4*)ga;
    int4 a1 = *(const int4*)(ga + 8);
    int4 b0 = *(const int4*)gb;
    int4 b1 = *(const int4*)(gb + 8);
    __syncthreads();  // previous iter's ds_reads retired before restage
    *(int4*)(As + srow * 32 + scol)     = a0;
    *(int4*)(As + srow * 32 + scol + 8) = a1;
    *(int4*)(Bs + srow * 32 + scol)     = b0;
    *(int4*)(Bs + srow * 32 + scol + 8) = b1;
    __syncthreads();

    bfv8 af[4], bfr[4];
#pragma unroll
    for (int mt = 0; mt < 4; mt++)
      af[mt] = *(const bfv8*)(As + (wm * 64 + mt * 16 + frow) * 32 + fk);
#pragma unroll
    for (int nt = 0; nt < 4; nt++)
      bfr[nt] = *(const bfv8*)(Bs + (wn * 64 + nt * 16 + frow) * 32 + fk);
#pragma unroll
    for (int mt = 0; mt < 4; mt++)
#pragma unroll
      for (int nt = 0; nt < 4; nt++)
        acc[mt][nt] = __builtin_amdgcn_mfma_f32_16x16x32_bf16(
            af[mt], bfr[nt], acc[mt][nt], 0, 0, 0);
  }
}

// QKV projections: z-dim picks W and destination; dst layout (B,H,T,D), bf16
__global__ __launch_bounds__(256) void gemm_qkv_kernel(
    const u16* __restrict__ X, const u16* __restrict__ Wq,
    const u16* __restrict__ Wk, const u16* __restrict__ Wv,
    u16* __restrict__ Qo, u16* __restrict__ Ko, u16* __restrict__ Vo) {
  __shared__ __align__(16) __bf16 As[128 * 32];
  __shared__ __align__(16) __bf16 Bs[128 * 32];
  const u16* W = (blockIdx.z == 0) ? Wq : (blockIdx.z == 1) ? Wk : Wv;
  u16* dst     = (blockIdx.z == 0) ? Qo : (blockIdx.z == 1) ? Ko : Vo;
  const int m0 = blockIdx.x * 128, n0 = blockIdx.y * 128;

  f32x4 acc[4][4];
#pragma unroll
  for (int i = 0; i < 4; i++)
#pragma unroll
    for (int j = 0; j < 4; j++) acc[i][j] = {0.f, 0.f, 0.f, 0.f};

  gemm_core(X, W, m0, n0, acc, As, Bs);

  const int lane = threadIdx.x & 63, wave = threadIdx.x >> 6;
  const int wm = wave >> 1, wn = wave & 1;
  const int quad = lane >> 4, col = lane & 15;
#pragma unroll
  for (int mt = 0; mt < 4; mt++)
#pragma unroll
    for (int nt = 0; nt < 4; nt++)
#pragma unroll
      for (int r = 0; r < 4; r++) {
        int m = m0 + wm * 64 + mt * 16 + quad * 4 + r;  // b*T + t
        int n = n0 + wn * 64 + nt * 16 + col;           // h*D + d
        int b = m >> 11, t = m & (T_SEQ - 1);
        int h = n >> 6, d = n & 63;
        dst[((size_t)(b * N_HEAD + h) * T_SEQ + t) * HEAD_D + d] =
            f2bf(acc[mt][nt][r]);
      }
}

// Output projection: out[m,n] row-major (B,T,C), fp32 output
__global__ __launch_bounds__(256) void gemm_out_kernel(
    const u16* __restrict__ Y, const u16* __restrict__ Wo,
    float* __restrict__ Out) {
  __shared__ __align__(16) __bf16 As[128 * 32];
  __shared__ __align__(16) __bf16 Bs[128 * 32];
  const int m0 = blockIdx.x * 128, n0 = blockIdx.y * 128;

  f32x4 acc[4][4];
#pragma unroll
  for (int i = 0; i < 4; i++)
#pragma unroll
    for (int j = 0; j < 4; j++) acc[i][j] = {0.f, 0.f, 0.f, 0.f};

  gemm_core(Y, Wo, m0, n0, acc, As, Bs);

  const int lane = threadIdx.x & 63, wave = threadIdx.x >> 6;
  const int wm = wave >> 1, wn = wave & 1;
  const int quad = lane >> 4, col = lane & 15;
#pragma unroll
  for (int mt = 0; mt < 4; mt++)
#pragma unroll
    for (int nt = 0; nt < 4; nt++)
#pragma unroll
      for (int r = 0; r < 4; r++) {
        int m = m0 + wm * 64 + mt * 16 + quad * 4 + r;
        int n = n0 + wn * 64 + nt * 16 + col;
        Out[(size_t)m * C_DIM + n] = acc[mt][nt][r];
      }
}

// ---------------------------------------------------------------------------
// Flash attention (causal), VALU fp32. One block = (b,h, 64-query tile).
// Thread grid 16x16: tq=tid>>4 owns q-rows tq*4..+3; tk=tid&15 owns
// k-cols (phase1) / d-cols (phase2) tk*4..+3.  LDS tiles transposed so both
// inner-loop operands are contiguous float4 (ds_read_b128).
// ---------------------------------------------------------------------------
#define LSV 68  // float stride: 16B-aligned, breaks 32-bank power-of-2

__global__ __launch_bounds__(256) void attn_kernel(
    const u16* __restrict__ Qg, const u16* __restrict__ Kg,
    const u16* __restrict__ Vg, u16* __restrict__ Yg) {
  __shared__ __align__(16) float Qt[64 * LSV];   // [d][q], pre-scaled
  __shared__ __align__(16) float KPt[64 * LSV];  // K as [d][k]; reused as P^T [k][q]
  __shared__ __align__(16) float Vs[64 * LSV];   // [k][d]

  const int tid = threadIdx.x;
  const int bh = blockIdx.x;            // b*16 + h
  const int b = bh >> 4, h = bh & 15;
  const int qt = blockIdx.y;
  const int q0 = qt * 64;

  const int srow = tid >> 2;            // staging: row 0..63
  const int scol = (tid & 3) * 16;      // staging: col group
  const int tq = tid >> 4;              // 0..15
  const int tk = tid & 15;              // 0..15

  {  // Q tile -> Qt[d][q], scaled
    const u16* gp = Qg + ((size_t)bh * T_SEQ + q0 + srow) * HEAD_D + scol;
    union { int4 v; u16 s[8]; } u0, u1;
    u0.v = *(const int4*)gp;
    u1.v = *(const int4*)(gp + 8);
#pragma unroll
    for (int i = 0; i < 8; i++) Qt[(scol + i) * LSV + srow] = bf2f(u0.s[i]) * SCALE;
#pragma unroll
    for (int i = 0; i < 8; i++) Qt[(scol + 8 + i) * LSV + srow] = bf2f(u1.s[i]) * SCALE;
  }

  float m_i[4], l_i[4], acc[4][4];
#pragma unroll
  for (int j = 0; j < 4; j++) {
    m_i[j] = -1e30f; l_i[j] = 0.f;
#pragma unroll
    for (int i = 0; i < 4; i++) acc[j][i] = 0.f;
  }

  for (int kt = 0; kt <= qt; kt++) {
    __syncthreads();  // prev phase2 done with KPt(P)/Vs; Q staging visible
    {  // stage K -> KPt[d][k] (transposed), V -> Vs[k][d]
      const u16* gk = Kg + ((size_t)bh * T_SEQ + kt * 64 + srow) * HEAD_D + scol;
      union { int4 v; u16 s[8]; } a0, a1;
      a0.v = *(const int4*)gk; a1.v = *(const int4*)(gk + 8);
#pragma unroll
      for (int i = 0; i < 8; i++) KPt[(scol + i) * LSV + srow] = bf2f(a0.s[i]);
#pragma unroll
      for (int i = 0; i < 8; i++) KPt[(scol + 8 + i) * LSV + srow] = bf2f(a1.s[i]);
      const u16* gv = Vg + ((size_t)bh * T_SEQ + kt * 64 + srow) * HEAD_D + scol;
      union { int4 v; u16 s[8]; } b0, b1;
      b0.v = *(const int4*)gv; b1.v = *(const int4*)(gv + 8);
#pragma unroll
      for (int i = 0; i < 8; i++) Vs[srow * LSV + scol + i] = bf2f(b0.s[i]);
#pragma unroll
      for (int i = 0; i < 8; i++) Vs[srow * LSV + scol + 8 + i] = bf2f(b1.s[i]);
    }
    __syncthreads();

    // phase 1: S = (Q*scale) K^T, 4x4 per thread
    float s[4][4];
#pragma unroll
    for (int j = 0; j < 4; j++)
#pragma unroll
      for (int i = 0; i < 4; i++) s[j][i] = 0.f;

    for (int d = 0; d < 64; d++) {
      const float4 qv = *(const float4*)&Qt[d * LSV + tq * 4];
      const float4 kv = *(const float4*)&KPt[d * LSV + tk * 4];
      const float qj[4] = {qv.x, qv.y, qv.z, qv.w};
      const float ki[4] = {kv.x, kv.y, kv.z, kv.w};
#pragma unroll
      for (int j = 0; j < 4; j++)
#pragma unroll
        for (int i = 0; i < 4; i++) s[j][i] = fmaf(qj[j], ki[i], s[j][i]);
    }

    if (kt == qt) {  // diagonal tile: causal mask
#pragma unroll
      for (int j = 0; j < 4; j++)
#pragma unroll
        for (int i = 0; i < 4; i++)
          if (tk * 4 + i > tq * 4 + j) s[j][i] = -1e30f;
    }

    // online softmax update (row stats across the 16 tk-lanes)
#pragma unroll
    for (int j = 0; j < 4; j++) {
      float rm = fmaxf(fmaxf(s[j][0], s[j][1]), fmaxf(s[j][2], s[j][3]));
      rm = fmaxf(rm, __shfl_xor(rm, 1));
      rm = fmaxf(rm, __shfl_xor(rm, 2));
      rm = fmaxf(rm, __shfl_xor(rm, 4));
      rm = fmaxf(rm, __shfl_xor(rm, 8));
      float mn = fmaxf(m_i[j], rm);
      float alpha = __expf(m_i[j] - mn);
      m_i[j] = mn;
      float rs = 0.f;
#pragma unroll
      for (int i = 0; i < 4; i++) {
        float p = __expf(s[j][i] - mn);
        s[j][i] = p;
        rs += p;
      }
      rs += __shfl_xor(rs, 1);
      rs += __shfl_xor(rs, 2);
      rs += __shfl_xor(rs, 4);
      rs += __shfl_xor(rs, 8);
      l_i[j] = l_i[j] * alpha + rs;
#pragma unroll
      for (int i = 0; i < 4; i++) acc[j][i] *= alpha;
    }

    __syncthreads();  // all lanes done reading KPt as K
#pragma unroll
    for (int j = 0; j < 4; j++)
#pragma unroll
      for (int i = 0; i < 4; i++)
        KPt[(tk * 4 + i) * LSV + tq * 4 + j] = s[j][i];  // P^T: [k][q]
    __syncthreads();

    // phase 2: O += P V
    for (int k = 0; k < 64; k++) {
      const float4 pv = *(const float4*)&KPt[k * LSV + tq * 4];
      const float4 vv = *(const float4*)&Vs[k * LSV + tk * 4];
      const float pj[4] = {pv.x, pv.y, pv.z, pv.w};
      const float vi[4] = {vv.x, vv.y, vv.z, vv.w};
#pragma unroll
      for (int j = 0; j < 4; j++)
#pragma unroll
        for (int i = 0; i < 4; i++) acc[j][i] = fmaf(pj[j], vi[i], acc[j][i]);
    }
  }

  // epilogue: y[b,t,h*D+d] = acc/l  (layout (B,T,C) for the final GEMM), bf16
#pragma unroll
  for (int j = 0; j < 4; j++) {
    float inv = 1.0f / l_i[j];
    size_t row = (size_t)q0 + tq * 4 + j;
    u16* yp = Yg + ((size_t)b * T_SEQ + row) * C_DIM + h * HEAD_D + tk * 4;
#pragma unroll
    for (int i = 0; i < 4; i++) yp[i] = f2bf(acc[j][i] * inv);
  }
}

extern "C" void kernel_launch(void* const* d_in, const int* in_sizes, int n_in,
                              void* d_out, int out_size, void* d_ws, size_t ws_size,
                              hipStream_t stream) {
  const float* x  = (const float*)d_in[0];   // fp32 per reference
  const float* Wq = (const float*)d_in[1];
  const float* Wk = (const float*)d_in[2];
  const float* Wv = (const float*)d_in[3];
  const float* Wo = (const float*)d_in[4];
  float* out = (float*)d_out;                // fp32 per reference

  const size_t NE = (size_t)B_SZ * T_SEQ * C_DIM;  // 8388608
  const size_t NW = (size_t)C_DIM * C_DIM;         // 1048576
  u16* xbf = (u16*)d_ws;
  u16* wqb = xbf + NE;
  u16* wkb = wqb + NW;
  u16* wvb = wkb + NW;
  u16* wob = wvb + NW;
  u16* qws = wob + NW;
  u16* kws = qws + NE;
  u16* vws = kws + NE;
  u16* yws = vws + NE;   // total ~92 MB of d_ws

  // fp32 -> bf16 conversion pre-pass
  cvt_kernel<<<(int)(NE / 4 / 256), 256, 0, stream>>>(x, xbf, (int)(NE / 4));
  cvt_kernel<<<(int)(NW / 4 / 256), 256, 0, stream>>>(Wq, wqb, (int)(NW / 4));
  cvt_kernel<<<(int)(NW / 4 / 256), 256, 0, stream>>>(Wk, wkb, (int)(NW / 4));
  cvt_kernel<<<(int)(NW / 4 / 256), 256, 0, stream>>>(Wv, wvb, (int)(NW / 4));
  cvt_kernel<<<(int)(NW / 4 / 256), 256, 0, stream>>>(Wo, wob, (int)(NW / 4));

  dim3 g1(T_SEQ * B_SZ / 128, C_DIM / 128, 3);  // 64 x 8 x 3
  gemm_qkv_kernel<<<g1, 256, 0, stream>>>(xbf, wqb, wkb, wvb, qws, kws, vws);

  dim3 g2(B_SZ * N_HEAD, T_SEQ / 64);           // 64 x 32
  attn_kernel<<<g2, 256, 0, stream>>>(qws, kws, vws, yws);

  dim3 g3(T_SEQ * B_SZ / 128, C_DIM / 128);     // 64 x 8
  gemm_out_kernel<<<g3, 256, 0, stream>>>(yws, wob, out);
}

// Round 4
// 301.505 us; speedup vs baseline: 2.8436x; 2.8436x over previous
//
#include <hip/hip_runtime.h>
#include <stdint.h>

// Problem constants
#define B_SZ   4
#define T_SEQ  2048
#define C_DIM  1024
#define N_HEAD 16
#define HEAD_D 64
#define SCALE  0.125f   // 1/sqrt(64), exact power of two (bf16-exact prescale)

typedef unsigned short u16;
typedef __bf16  bfv8  __attribute__((ext_vector_type(8)));
typedef float   f32x4 __attribute__((ext_vector_type(4)));

__device__ __forceinline__ float bf2f(u16 v) {
  union { unsigned int i; float f; } u; u.i = ((unsigned int)v) << 16; return u.f;
}
__device__ __forceinline__ u16 f2bf(float f) {
  union { float f; unsigned int i; } u; u.f = f;
  unsigned int r = u.i + 0x7FFFu + ((u.i >> 16) & 1u);  // RNE
  return (u16)(r >> 16);
}

// fp32 -> bf16 elementwise
__global__ __launch_bounds__(256) void cvt_kernel(const float* __restrict__ src,
                                                  u16* __restrict__ dst, int n4) {
  int i = blockIdx.x * blockDim.x + threadIdx.x;
  if (i < n4) {
    float4 v = ((const float4*)src)[i];
    ushort4 o;
    o.x = f2bf(v.x); o.y = f2bf(v.y); o.z = f2bf(v.z); o.w = f2bf(v.w);
    ((ushort4*)dst)[i] = o;
  }
}

// ---------------------------------------------------------------------------
// NT GEMM core: C[m,n] = sum_k A[m,k]*Bw[n,k]; 128x128 tile, BK=32,
// 4 waves 2x2, 4x4 of 16x16x32 MFMA each. (Round-3 verified.)
// ---------------------------------------------------------------------------
__device__ __forceinline__ void gemm_core(const u16* __restrict__ A,
                                          const u16* __restrict__ Bw,
                                          int m0, int n0,
                                          f32x4 acc[4][4],
                                          __bf16* As, __bf16* Bs) {
  const int tid  = threadIdx.x;
  const int wave = tid >> 6;
  const int lane = tid & 63;
  const int srow = tid >> 1;
  const int scol = (tid & 1) * 16;
  const int frow = lane & 15;
  const int fk   = (lane >> 4) * 8;
  const int wm   = wave >> 1, wn = wave & 1;

  for (int k0 = 0; k0 < C_DIM; k0 += 32) {
    const u16* ga = A  + (size_t)(m0 + srow) * C_DIM + k0 + scol;
    const u16* gb = Bw + (size_t)(n0 + srow) * C_DIM + k0 + scol;
    int4 a0 = *(const int4*)ga;
    int4 a1 = *(const int4*)(ga + 8);
    int4 b0 = *(const int4*)gb;
    int4 b1 = *(const int4*)(gb + 8);
    __syncthreads();
    *(int4*)(As + srow * 32 + scol)     = a0;
    *(int4*)(As + srow * 32 + scol + 8) = a1;
    *(int4*)(Bs + srow * 32 + scol)     = b0;
    *(int4*)(Bs + srow * 32 + scol + 8) = b1;
    __syncthreads();

    bfv8 af[4], bfr[4];
#pragma unroll
    for (int mt = 0; mt < 4; mt++)
      af[mt] = *(const bfv8*)(As + (wm * 64 + mt * 16 + frow) * 32 + fk);
#pragma unroll
    for (int nt = 0; nt < 4; nt++)
      bfr[nt] = *(const bfv8*)(Bs + (wn * 64 + nt * 16 + frow) * 32 + fk);
#pragma unroll
    for (int mt = 0; mt < 4; mt++)
#pragma unroll
      for (int nt = 0; nt < 4; nt++)
        acc[mt][nt] = __builtin_amdgcn_mfma_f32_16x16x32_bf16(
            af[mt], bfr[nt], acc[mt][nt], 0, 0, 0);
  }
}

// QKV projections. Q,K -> (B,H,T,D). V -> TRANSPOSED (B,H,D,T) with packed
// 4-token stores (the 4 C-regs per lane are consecutive tokens).
__global__ __launch_bounds__(256) void gemm_qkv_kernel(
    const u16* __restrict__ X, const u16* __restrict__ Wq,
    const u16* __restrict__ Wk, const u16* __restrict__ Wv,
    u16* __restrict__ Qo, u16* __restrict__ Ko, u16* __restrict__ Vo) {
  __shared__ __align__(16) __bf16 As[128 * 32];
  __shared__ __align__(16) __bf16 Bs[128 * 32];
  const u16* W = (blockIdx.z == 0) ? Wq : (blockIdx.z == 1) ? Wk : Wv;
  u16* dst     = (blockIdx.z == 0) ? Qo : (blockIdx.z == 1) ? Ko : Vo;
  const int m0 = blockIdx.x * 128, n0 = blockIdx.y * 128;

  f32x4 acc[4][4];
#pragma unroll
  for (int i = 0; i < 4; i++)
#pragma unroll
    for (int j = 0; j < 4; j++) acc[i][j] = {0.f, 0.f, 0.f, 0.f};

  gemm_core(X, W, m0, n0, acc, As, Bs);

  const int lane = threadIdx.x & 63, wave = threadIdx.x >> 6;
  const int wm = wave >> 1, wn = wave & 1;
  const int quad = lane >> 4, col = lane & 15;
  if (blockIdx.z == 2) {
    // V^T: (B,H,D,T)
#pragma unroll
    for (int mt = 0; mt < 4; mt++)
#pragma unroll
      for (int nt = 0; nt < 4; nt++) {
        int t4 = m0 + wm * 64 + mt * 16 + quad * 4;  // 4 consecutive tokens
        int n  = n0 + wn * 64 + nt * 16 + col;
        int b = t4 >> 11, t = t4 & (T_SEQ - 1);
        int h = n >> 6, d = n & 63;
        ushort4 o;
        o.x = f2bf(acc[mt][nt][0]); o.y = f2bf(acc[mt][nt][1]);
        o.z = f2bf(acc[mt][nt][2]); o.w = f2bf(acc[mt][nt][3]);
        *(ushort4*)(dst + (((size_t)(b * N_HEAD + h) * HEAD_D + d) * T_SEQ + t)) = o;
      }
  } else {
#pragma unroll
    for (int mt = 0; mt < 4; mt++)
#pragma unroll
      for (int nt = 0; nt < 4; nt++)
#pragma unroll
        for (int r = 0; r < 4; r++) {
          int m = m0 + wm * 64 + mt * 16 + quad * 4 + r;
          int n = n0 + wn * 64 + nt * 16 + col;
          int b = m >> 11, t = m & (T_SEQ - 1);
          int h = n >> 6, d = n & 63;
          dst[((size_t)(b * N_HEAD + h) * T_SEQ + t) * HEAD_D + d] =
              f2bf(acc[mt][nt][r]);
        }
  }
}

// Output projection: (B,T,C) fp32 output
__global__ __launch_bounds__(256) void gemm_out_kernel(
    const u16* __restrict__ Y, const u16* __restrict__ Wo,
    float* __restrict__ Out) {
  __shared__ __align__(16) __bf16 As[128 * 32];
  __shared__ __align__(16) __bf16 Bs[128 * 32];
  const int m0 = blockIdx.x * 128, n0 = blockIdx.y * 128;

  f32x4 acc[4][4];
#pragma unroll
  for (int i = 0; i < 4; i++)
#pragma unroll
    for (int j = 0; j < 4; j++) acc[i][j] = {0.f, 0.f, 0.f, 0.f};

  gemm_core(Y, Wo, m0, n0, acc, As, Bs);

  const int lane = threadIdx.x & 63, wave = threadIdx.x >> 6;
  const int wm = wave >> 1, wn = wave & 1;
  const int quad = lane >> 4, col = lane & 15;
#pragma unroll
  for (int mt = 0; mt < 4; mt++)
#pragma unroll
    for (int nt = 0; nt < 4; nt++)
#pragma unroll
      for (int r = 0; r < 4; r++) {
        int m = m0 + wm * 64 + mt * 16 + quad * 4 + r;
        int n = n0 + wn * 64 + nt * 16 + col;
        Out[(size_t)m * C_DIM + n] = acc[mt][nt][r];
      }
}

// ---------------------------------------------------------------------------
// MFMA flash attention (causal). Block = (b,h) x 128-query tile; 4 waves,
// each owns 32 q (2 n-tiles of 16). K-loop over 64-key tiles.
//   S^T = K·Q^T   (A=Ks[key][d], B=Qs[q][d])  -> C col = q (lane&15)
//   online softmax: state per lane (2 q), reduce across quads (xor16/32)
//   P^T -> LDS Ps[q][key] (packed 8B writes), bf16
//   O^T = V^T·P   (A=Vt[d][key], B=Ps[q][key]) -> C col = q, row = d
// All LDS tiles: row stride 64 elems (128B), XOR-granule swizzle
// (granule ^ (row&7)) so every wave b128 access spreads across all 32 banks.
// ---------------------------------------------------------------------------
#define ATT_Q 128

__global__ __launch_bounds__(256) void attn_kernel(
    const u16* __restrict__ Qg, const u16* __restrict__ Kg,
    const u16* __restrict__ Vtg, u16* __restrict__ Yg) {
  __shared__ __align__(16) u16 Qs[128 * 64];
  __shared__ __align__(16) u16 Ks[64 * 64];
  __shared__ __align__(16) u16 Vt[64 * 64];
  __shared__ __align__(16) u16 Ps[128 * 64];

  const int tid = threadIdx.x;
  const int wave = tid >> 6, lane = tid & 63;
  const int quad = lane >> 4, l15 = lane & 15;
  const int bh = blockIdx.x;            // b*16 + h
  const int b = bh >> 4, h = bh & 15;
  const int qt = gridDim.y - 1 - blockIdx.y;  // heavy tiles dispatch first
  const int q0 = qt * ATT_Q;

  // ---- stage Q tile (pre-scaled by 0.125, exact in bf16) ----
  {
    const int row = tid >> 1;            // 0..127
    const int c0 = (tid & 1) * 32;
    const u16* gp = Qg + ((size_t)bh * T_SEQ + q0 + row) * HEAD_D + c0;
#pragma unroll
    for (int g = 0; g < 4; g++) {
      union { int4 v; u16 s[8]; } u;
      u.v = *(const int4*)(gp + g * 8);
      u16 tmp[8];
#pragma unroll
      for (int i = 0; i < 8; i++) tmp[i] = f2bf(bf2f(u.s[i]) * SCALE);
      int pg = ((c0 >> 3) + g) ^ (row & 7);
      *(int4*)(Qs + row * 64 + pg * 8) = *(int4*)tmp;
    }
  }
  __syncthreads();

  // hoist Q B-frags (fixed for the whole K-loop): 2 n-tiles x 2 k-steps
  bfv8 qb[2][2];
#pragma unroll
  for (int nt = 0; nt < 2; nt++)
#pragma unroll
    for (int ks = 0; ks < 2; ks++) {
      int q = wave * 32 + nt * 16 + l15;
      int pg = (ks * 4 + quad) ^ (q & 7);
      qb[nt][ks] = *(const bfv8*)(Qs + q * 64 + pg * 8);
    }

  float m_i[2] = {-1e30f, -1e30f}, l_i[2] = {0.f, 0.f};
  f32x4 ao[4][2];
#pragma unroll
  for (int mt = 0; mt < 4; mt++)
#pragma unroll
    for (int nt = 0; nt < 2; nt++) ao[mt][nt] = {0.f, 0.f, 0.f, 0.f};

  const int ktmax = 2 * qt + 1;
  for (int kt = 0; kt <= ktmax; kt++) {
    __syncthreads();  // prev iter done reading Ks/Vt
    {  // stage K[key][d] and Vt[d][key], swizzled
      const int row = tid >> 2;          // 0..63
      const int c0 = (tid & 3) * 16;
      const u16* gk = Kg  + ((size_t)bh * T_SEQ + kt * 64 + row) * HEAD_D + c0;
      const u16* gv = Vtg + ((size_t)bh * HEAD_D + row) * T_SEQ + kt * 64 + c0;
#pragma unroll
      for (int gg = 0; gg < 2; gg++) {
        int4 kv = *(const int4*)(gk + gg * 8);
        int4 vv = *(const int4*)(gv + gg * 8);
        int pg = ((c0 >> 3) + gg) ^ (row & 7);
        *(int4*)(Ks + row * 64 + pg * 8) = kv;
        *(int4*)(Vt + row * 64 + pg * 8) = vv;
      }
    }
    __syncthreads();

    // ---- S^T = K · Q^T : 4 key-tiles x 2 q-tiles x 2 k-steps ----
    f32x4 as[4][2];
#pragma unroll
    for (int mt = 0; mt < 4; mt++)
#pragma unroll
      for (int nt = 0; nt < 2; nt++) as[mt][nt] = {0.f, 0.f, 0.f, 0.f};

#pragma unroll
    for (int mt = 0; mt < 4; mt++) {
      bfv8 ka[2];
#pragma unroll
      for (int ks = 0; ks < 2; ks++) {
        int key = mt * 16 + l15;
        int pg = (ks * 4 + quad) ^ (key & 7);
        ka[ks] = *(const bfv8*)(Ks + key * 64 + pg * 8);
      }
#pragma unroll
      for (int nt = 0; nt < 2; nt++)
#pragma unroll
        for (int ks = 0; ks < 2; ks++)
          as[mt][nt] = __builtin_amdgcn_mfma_f32_16x16x32_bf16(
              ka[ks], qb[nt][ks], as[mt][nt], 0, 0, 0);
    }

    // ---- online softmax (per lane: 2 q-rows, 16 keys each) ----
    const bool diag = (kt >= 2 * qt);  // last two tiles touch the diagonal
#pragma unroll
    for (int nt = 0; nt < 2; nt++) {
      const int q_l = wave * 32 + nt * 16 + l15;
      const int q_g = q0 + q_l;
      float sv[16];
#pragma unroll
      for (int mt = 0; mt < 4; mt++)
#pragma unroll
        for (int r = 0; r < 4; r++) {
          float s = as[mt][nt][r];
          if (diag) {
            int key_g = kt * 64 + mt * 16 + quad * 4 + r;
            if (key_g > q_g) s = -1e30f;
          }
          sv[mt * 4 + r] = s;
        }
      float rm = sv[0];
#pragma unroll
      for (int i = 1; i < 16; i++) rm = fmaxf(rm, sv[i]);
      rm = fmaxf(rm, __shfl_xor(rm, 16));
      rm = fmaxf(rm, __shfl_xor(rm, 32));
      float mn = fmaxf(m_i[nt], rm);
      float alpha = __expf(m_i[nt] - mn);
      m_i[nt] = mn;
      float rs = 0.f;
      u16 pb[16];
#pragma unroll
      for (int i = 0; i < 16; i++) {
        float p = __expf(sv[i] - mn);
        rs += p;
        pb[i] = f2bf(p);
      }
      rs += __shfl_xor(rs, 16);
      rs += __shfl_xor(rs, 32);
      l_i[nt] = l_i[nt] * alpha + rs;
#pragma unroll
      for (int mt = 0; mt < 4; mt++) ao[mt][nt] *= alpha;
      // write P^T -> Ps[q][key]: 4 packed 8B stores (keys mt*16+quad*4..+3)
#pragma unroll
      for (int mt = 0; mt < 4; mt++) {
        int pg = (2 * mt + (quad >> 1)) ^ (q_l & 7);
        ushort4 o; o.x = pb[mt*4+0]; o.y = pb[mt*4+1];
        o.z = pb[mt*4+2]; o.w = pb[mt*4+3];
        *(ushort4*)(Ps + q_l * 64 + pg * 8 + (quad & 1) * 4) = o;
      }
    }
    __syncthreads();  // P visible (conservative; reads are same-wave)

    // ---- O^T += V^T · P : 4 d-tiles x 2 q-tiles x 2 k-steps ----
    bfv8 pf[2][2];
#pragma unroll
    for (int nt = 0; nt < 2; nt++)
#pragma unroll
      for (int ks = 0; ks < 2; ks++) {
        int q_l = wave * 32 + nt * 16 + l15;
        int pg = (ks * 4 + quad) ^ (q_l & 7);
        pf[nt][ks] = *(const bfv8*)(Ps + q_l * 64 + pg * 8);
      }
#pragma unroll
    for (int mt = 0; mt < 4; mt++) {
      bfv8 va[2];
#pragma unroll
      for (int ks = 0; ks < 2; ks++) {
        int d = mt * 16 + l15;
        int pg = (ks * 4 + quad) ^ (d & 7);
        va[ks] = *(const bfv8*)(Vt + d * 64 + pg * 8);
      }
#pragma unroll
      for (int nt = 0; nt < 2; nt++)
#pragma unroll
        for (int ks = 0; ks < 2; ks++)
          ao[mt][nt] = __builtin_amdgcn_mfma_f32_16x16x32_bf16(
              va[ks], pf[nt][ks], ao[mt][nt], 0, 0, 0);
    }
  }

  // ---- epilogue: Y[b, q, h*64+d] = O^T/l, packed 8B stores ----
#pragma unroll
  for (int nt = 0; nt < 2; nt++) {
    float inv = 1.0f / l_i[nt];
    int q = q0 + wave * 32 + nt * 16 + l15;
    u16* yp = Yg + ((size_t)b * T_SEQ + q) * C_DIM + h * HEAD_D;
#pragma unroll
    for (int mt = 0; mt < 4; mt++) {
      int d = mt * 16 + quad * 4;
      ushort4 o;
      o.x = f2bf(ao[mt][nt][0] * inv); o.y = f2bf(ao[mt][nt][1] * inv);
      o.z = f2bf(ao[mt][nt][2] * inv); o.w = f2bf(ao[mt][nt][3] * inv);
      *(ushort4*)(yp + d) = o;
    }
  }
}

extern "C" void kernel_launch(void* const* d_in, const int* in_sizes, int n_in,
                              void* d_out, int out_size, void* d_ws, size_t ws_size,
                              hipStream_t stream) {
  const float* x  = (const float*)d_in[0];
  const float* Wq = (const float*)d_in[1];
  const float* Wk = (const float*)d_in[2];
  const float* Wv = (const float*)d_in[3];
  const float* Wo = (const float*)d_in[4];
  float* out = (float*)d_out;

  const size_t NE = (size_t)B_SZ * T_SEQ * C_DIM;  // 8388608
  const size_t NW = (size_t)C_DIM * C_DIM;         // 1048576
  u16* xbf = (u16*)d_ws;
  u16* wqb = xbf + NE;
  u16* wkb = wqb + NW;
  u16* wvb = wkb + NW;
  u16* wob = wvb + NW;
  u16* qws = wob + NW;
  u16* kws = qws + NE;
  u16* vws = kws + NE;   // V^T layout (B,H,D,T)
  u16* yws = vws + NE;

  cvt_kernel<<<(int)(NE / 4 / 256), 256, 0, stream>>>(x, xbf, (int)(NE / 4));
  cvt_kernel<<<(int)(NW / 4 / 256), 256, 0, stream>>>(Wq, wqb, (int)(NW / 4));
  cvt_kernel<<<(int)(NW / 4 / 256), 256, 0, stream>>>(Wk, wkb, (int)(NW / 4));
  cvt_kernel<<<(int)(NW / 4 / 256), 256, 0, stream>>>(Wv, wvb, (int)(NW / 4));
  cvt_kernel<<<(int)(NW / 4 / 256), 256, 0, stream>>>(Wo, wob, (int)(NW / 4));

  dim3 g1(T_SEQ * B_SZ / 128, C_DIM / 128, 3);  // 64 x 8 x 3
  gemm_qkv_kernel<<<g1, 256, 0, stream>>>(xbf, wqb, wkb, wvb, qws, kws, vws);

  dim3 g2(B_SZ * N_HEAD, T_SEQ / ATT_Q);        // 64 x 16
  attn_kernel<<<g2, 256, 0, stream>>>(qws, kws, vws, yws);

  dim3 g3(T_SEQ * B_SZ / 128, C_DIM / 128);     // 64 x 8
  gemm_out_kernel<<<g3, 256, 0, stream>>>(yws, wob, out);
}

// Round 5
// 280.706 us; speedup vs baseline: 3.0543x; 1.0741x over previous
//
#include <hip/hip_runtime.h>
#include <stdint.h>

// Problem constants
#define B_SZ   4
#define T_SEQ  2048
#define C_DIM  1024
#define N_HEAD 16
#define HEAD_D 64
#define SCALE  0.125f                 // 1/sqrt(64)
#define QSCALE 0.18033688011112042f  // SCALE * log2(e): attn runs in exp2 domain

typedef unsigned short u16;
typedef unsigned int   u32;
typedef __bf16  bfv8  __attribute__((ext_vector_type(8)));
typedef float   f32x4 __attribute__((ext_vector_type(4)));

__device__ __forceinline__ float bf2f(u16 v) {
  union { u32 i; float f; } u; u.i = ((u32)v) << 16; return u.f;
}
__device__ __forceinline__ u16 f2bf(float f) {
  union { float f; u32 i; } u; u.f = f;
  u32 r = u.i + 0x7FFFu + ((u.i >> 16) & 1u);  // RNE
  return (u16)(r >> 16);
}
// pack 2 floats -> 2 bf16 in one u32, round-half-up (1-ulp, bias-free enough;
// ~5 VALU vs ~10 for RNE pair)
__device__ __forceinline__ u32 pkbf16(float a, float b) {
  union { float f; u32 i; } ua, ub; ua.f = a; ub.f = b;
  return ((ua.i + 0x8000u) >> 16) | ((ub.i + 0x8000u) & 0xFFFF0000u);
}
__device__ __forceinline__ float fexp2(float x) {
#if __has_builtin(__builtin_amdgcn_exp2f)
  return __builtin_amdgcn_exp2f(x);       // bare v_exp_f32
#else
  return __expf(x * 0.69314718f);          // exp(ln2*x) == 2^x
#endif
}
// async global->LDS, 16B/lane; LDS dest = wave-uniform base + lane*16
__device__ __forceinline__ void gload_lds16(const u16* g, u16* l) {
  __builtin_amdgcn_global_load_lds(
      (__attribute__((address_space(1))) void*)(void*)g,
      (__attribute__((address_space(3))) void*)(void*)l, 16, 0, 0);
}

// fp32 -> bf16 elementwise (x)
__global__ __launch_bounds__(256) void cvt_kernel(const float* __restrict__ src,
                                                  u16* __restrict__ dst, int n4) {
  int i = blockIdx.x * 256 + threadIdx.x;
  if (i < n4) {
    float4 v = ((const float4*)src)[i];
    int2 o; o.x = (int)pkbf16(v.x, v.y); o.y = (int)pkbf16(v.z, v.w);
    ((int2*)dst)[i] = o;
  }
}
// all four weights in one launch (dst regions contiguous)
__global__ __launch_bounds__(256) void cvt_w_kernel(
    const float* __restrict__ W0, const float* __restrict__ W1,
    const float* __restrict__ W2, const float* __restrict__ W3,
    u16* __restrict__ dst) {
  const float* s = (blockIdx.y == 0) ? W0 : (blockIdx.y == 1) ? W1
                 : (blockIdx.y == 2) ? W2 : W3;
  u16* d = dst + (size_t)blockIdx.y * (C_DIM * C_DIM);
  int i = blockIdx.x * 256 + threadIdx.x;
  float4 v = ((const float4*)s)[i];
  int2 o; o.x = (int)pkbf16(v.x, v.y); o.y = (int)pkbf16(v.z, v.w);
  ((int2*)d)[i] = o;
}

// ---------------------------------------------------------------------------
// NT GEMM core: C[m,n] = sum_k A[m,k]*Bw[n,k]; 128x128 tile, BK=32,
// 4 waves 2x2, 4x4 of 16x16x32 MFMA. Staging via global_load_lds width=16
// (m97 pattern): lane i of wave w writes As[w*32 + (i>>2)][(i&3)*8 .. +8).
// ---------------------------------------------------------------------------
__device__ __forceinline__ void gemm_core(const u16* __restrict__ A,
                                          const u16* __restrict__ Bw,
                                          int m0, int n0,
                                          f32x4 acc[4][4],
                                          u16* As, u16* Bs) {
  const int tid  = threadIdx.x;
  const int wave = tid >> 6;
  const int lane = tid & 63;
  const int lrow = lane >> 2;
  const int lcol = (lane & 3) * 8;
  const int frow = lane & 15;
  const int fk   = (lane >> 4) * 8;
  const int wm   = wave >> 1, wn = wave & 1;

  for (int k0 = 0; k0 < C_DIM; k0 += 32) {
    __syncthreads();  // prev iter's ds_reads retired before restage
    const u16* ga = A + (size_t)(m0 + wave * 32 + lrow) * C_DIM + k0 + lcol;
    gload_lds16(ga,              As + (wave * 32) * 32);
    gload_lds16(ga + 16 * C_DIM, As + (wave * 32 + 16) * 32);
    const u16* gb = Bw + (size_t)(n0 + wave * 32 + lrow) * C_DIM + k0 + lcol;
    gload_lds16(gb,              Bs + (wave * 32) * 32);
    gload_lds16(gb + 16 * C_DIM, Bs + (wave * 32 + 16) * 32);
    __syncthreads();  // vmcnt(0) drained before barrier -> LDS visible

    bfv8 af[4], bfr[4];
#pragma unroll
    for (int mt = 0; mt < 4; mt++)
      af[mt] = *(const bfv8*)(As + (wm * 64 + mt * 16 + frow) * 32 + fk);
#pragma unroll
    for (int nt = 0; nt < 4; nt++)
      bfr[nt] = *(const bfv8*)(Bs + (wn * 64 + nt * 16 + frow) * 32 + fk);
#pragma unroll
    for (int mt = 0; mt < 4; mt++)
#pragma unroll
      for (int nt = 0; nt < 4; nt++)
        acc[mt][nt] = __builtin_amdgcn_mfma_f32_16x16x32_bf16(
            af[mt], bfr[nt], acc[mt][nt], 0, 0, 0);
  }
}

// QKV projections. Q (pre-scaled by QSCALE), K -> (B,H,T,D).
// V -> (B,H,D,T) via wave-private LDS bounce -> fully coalesced 16B stores.
__global__ __launch_bounds__(256) void gemm_qkv_kernel(
    const u16* __restrict__ X, const u16* __restrict__ Wq,
    const u16* __restrict__ Wk, const u16* __restrict__ Wv,
    u16* __restrict__ Qo, u16* __restrict__ Ko, u16* __restrict__ Vo) {
  __shared__ __align__(16) u16 smem[8192];  // As | Bs, reused as V-bounce buf
  u16* As = smem;
  u16* Bs = smem + 4096;
  const u16* W = (blockIdx.z == 0) ? Wq : (blockIdx.z == 1) ? Wk : Wv;
  u16* dst     = (blockIdx.z == 0) ? Qo : (blockIdx.z == 1) ? Ko : Vo;
  const int m0 = blockIdx.x * 128, n0 = blockIdx.y * 128;

  f32x4 acc[4][4];
#pragma unroll
  for (int i = 0; i < 4; i++)
#pragma unroll
    for (int j = 0; j < 4; j++) acc[i][j] = {0.f, 0.f, 0.f, 0.f};

  gemm_core(X, W, m0, n0, acc, As, Bs);

  const int lane = threadIdx.x & 63, wave = threadIdx.x >> 6;
  const int wm = wave >> 1, wn = wave & 1;
  const int quad = lane >> 4, col = lane & 15;

  if (blockIdx.z == 2) {
    // ---- V^T (B,H,D,T) via wave-private LDS bounce ----
    __syncthreads();  // all waves done with As/Bs fragment reads
    u16* buf = smem + wave * 2048;  // 32 rows(d) x 16 granules(8B over t)
#pragma unroll
    for (int c = 0; c < 2; c++) {
#pragma unroll
      for (int mt = 0; mt < 4; mt++)
#pragma unroll
        for (int nn = 0; nn < 2; nn++) {
          int nt = 2 * c + nn;
          int ln = nn * 16 + col;           // local d row 0..31
          int g  = mt * 4 + quad;           // t-granule 0..15 (4 tokens)
          int gp = g ^ (ln & 15);           // bank swizzle
          int2 o;
          o.x = (int)pkbf16(acc[mt][nt][0], acc[mt][nt][1]);
          o.y = (int)pkbf16(acc[mt][nt][2], acc[mt][nt][3]);
          *(int2*)(buf + ln * 64 + gp * 4) = o;
        }
      // wave-private read-back + coalesced store (8 lanes -> 128B per d row)
#pragma unroll
      for (int rr = 0; rr < 4; rr++) {
        int ln  = rr * 8 + (lane >> 3);
        int seg = lane & 7;
        int g0 = (2 * seg) ^ (ln & 15), g1 = (2 * seg + 1) ^ (ln & 15);
        int2 a  = *(const int2*)(buf + ln * 64 + g0 * 4);
        int2 bv = *(const int2*)(buf + ln * 64 + g1 * 4);
        int m = m0 + wm * 64 + seg * 8;
        int bb = m >> 11, t = m & (T_SEQ - 1);
        int n = n0 + wn * 64 + c * 32 + ln;
        int h = n >> 6, d = n & 63;
        int4 o; o.x = a.x; o.y = a.y; o.z = bv.x; o.w = bv.y;
        *(int4*)(Vo + (((size_t)(bb * N_HEAD + h) * HEAD_D + d) * T_SEQ + t)) = o;
      }
    }
  } else {
    const float sc = (blockIdx.z == 0) ? QSCALE : 1.0f;
#pragma unroll
    for (int mt = 0; mt < 4; mt++)
#pragma unroll
      for (int nt = 0; nt < 4; nt++)
#pragma unroll
        for (int r = 0; r < 4; r++) {
          int m = m0 + wm * 64 + mt * 16 + quad * 4 + r;
          int n = n0 + wn * 64 + nt * 16 + col;
          int b = m >> 11, t = m & (T_SEQ - 1);
          int h = n >> 6, d = n & 63;
          dst[((size_t)(b * N_HEAD + h) * T_SEQ + t) * HEAD_D + d] =
              f2bf(acc[mt][nt][r] * sc);
        }
  }
}

// Output projection: (B,T,C) fp32 output
__global__ __launch_bounds__(256) void gemm_out_kernel(
    const u16* __restrict__ Y, const u16* __restrict__ Wo,
    float* __restrict__ Out) {
  __shared__ __align__(16) u16 smem[8192];
  u16* As = smem; u16* Bs = smem + 4096;
  const int m0 = blockIdx.x * 128, n0 = blockIdx.y * 128;

  f32x4 acc[4][4];
#pragma unroll
  for (int i = 0; i < 4; i++)
#pragma unroll
    for (int j = 0; j < 4; j++) acc[i][j] = {0.f, 0.f, 0.f, 0.f};

  gemm_core(Y, Wo, m0, n0, acc, As, Bs);

  const int lane = threadIdx.x & 63, wave = threadIdx.x >> 6;
  const int wm = wave >> 1, wn = wave & 1;
  const int quad = lane >> 4, col = lane & 15;
#pragma unroll
  for (int mt = 0; mt < 4; mt++)
#pragma unroll
    for (int nt = 0; nt < 4; nt++)
#pragma unroll
      for (int r = 0; r < 4; r++) {
        int m = m0 + wm * 64 + mt * 16 + quad * 4 + r;
        int n = n0 + wn * 64 + nt * 16 + col;
        Out[(size_t)m * C_DIM + n] = acc[mt][nt][r];
      }
}

// ---------------------------------------------------------------------------
// MFMA flash attention (causal), exp2 domain (Q pre-scaled by SCALE*log2e).
// Block = (b,h) x 128-query tile; 4 waves x 32 q. K-loop over 64-key tiles.
//   S^T = K·Q^T ; softmax per lane (2 q) w/ quad-reduce; P^T -> LDS (bf16);
//   O^T = V^T·P ; epilogue transposed through LDS (coalesced 16B stores).
// ---------------------------------------------------------------------------
#define ATT_Q 128

__global__ __launch_bounds__(256) void attn_kernel(
    const u16* __restrict__ Qg, const u16* __restrict__ Kg,
    const u16* __restrict__ Vtg, u16* __restrict__ Yg) {
  __shared__ __align__(16) u16 Qs[128 * 64];   // reused as Y-bounce at end
  __shared__ __align__(16) u16 Ks[64 * 64];
  __shared__ __align__(16) u16 Vt[64 * 64];
  __shared__ __align__(16) u16 Ps[128 * 64];

  const int tid = threadIdx.x;
  const int wave = tid >> 6, lane = tid & 63;
  const int quad = lane >> 4, l15 = lane & 15;
  const int bh = blockIdx.x;
  const int b = bh >> 4, h = bh & 15;
  const int qt = gridDim.y - 1 - blockIdx.y;   // heavy tiles first
  const int q0 = qt * ATT_Q;

  // ---- stage Q tile (already exp2-prescaled) ----
  {
    const int row = tid >> 1;
    const int c0 = (tid & 1) * 32;
    const u16* gp = Qg + ((size_t)bh * T_SEQ + q0 + row) * HEAD_D + c0;
#pragma unroll
    for (int g = 0; g < 4; g++) {
      int4 v = *(const int4*)(gp + g * 8);
      int pg = ((c0 >> 3) + g) ^ (row & 7);
      *(int4*)(Qs + row * 64 + pg * 8) = v;
    }
  }
  __syncthreads();

  bfv8 qb[2][2];
#pragma unroll
  for (int nt = 0; nt < 2; nt++)
#pragma unroll
    for (int ks = 0; ks < 2; ks++) {
      int q = wave * 32 + nt * 16 + l15;
      int pg = (ks * 4 + quad) ^ (q & 7);
      qb[nt][ks] = *(const bfv8*)(Qs + q * 64 + pg * 8);
    }

  float m_i[2] = {-1e30f, -1e30f}, l_i[2] = {0.f, 0.f};
  f32x4 ao[4][2];
#pragma unroll
  for (int mt = 0; mt < 4; mt++)
#pragma unroll
    for (int nt = 0; nt < 2; nt++) ao[mt][nt] = {0.f, 0.f, 0.f, 0.f};

  const int ktmax = 2 * qt + 1;
  for (int kt = 0; kt <= ktmax; kt++) {
    __syncthreads();
    {  // stage K[key][d], Vt[d][key], swizzled
      const int row = tid >> 2;
      const int c0 = (tid & 3) * 16;
      const u16* gk = Kg  + ((size_t)bh * T_SEQ + kt * 64 + row) * HEAD_D + c0;
      const u16* gv = Vtg + ((size_t)bh * HEAD_D + row) * T_SEQ + kt * 64 + c0;
#pragma unroll
      for (int gg = 0; gg < 2; gg++) {
        int4 kv = *(const int4*)(gk + gg * 8);
        int4 vv = *(const int4*)(gv + gg * 8);
        int pg = ((c0 >> 3) + gg) ^ (row & 7);
        *(int4*)(Ks + row * 64 + pg * 8) = kv;
        *(int4*)(Vt + row * 64 + pg * 8) = vv;
      }
    }
    __syncthreads();

    // ---- S^T = K · Q^T ----
    f32x4 as[4][2];
#pragma unroll
    for (int mt = 0; mt < 4; mt++)
#pragma unroll
      for (int nt = 0; nt < 2; nt++) as[mt][nt] = {0.f, 0.f, 0.f, 0.f};
#pragma unroll
    for (int mt = 0; mt < 4; mt++) {
      bfv8 ka[2];
#pragma unroll
      for (int ks = 0; ks < 2; ks++) {
        int key = mt * 16 + l15;
        int pg = (ks * 4 + quad) ^ (key & 7);
        ka[ks] = *(const bfv8*)(Ks + key * 64 + pg * 8);
      }
#pragma unroll
      for (int nt = 0; nt < 2; nt++)
#pragma unroll
        for (int ks = 0; ks < 2; ks++)
          as[mt][nt] = __builtin_amdgcn_mfma_f32_16x16x32_bf16(
              ka[ks], qb[nt][ks], as[mt][nt], 0, 0, 0);
    }

    // ---- online softmax (exp2 domain) ----
    const bool diag = (kt >= 2 * qt);
#pragma unroll
    for (int nt = 0; nt < 2; nt++) {
      const int q_l = wave * 32 + nt * 16 + l15;
      const int q_g = q0 + q_l;
      float sv[16];
#pragma unroll
      for (int mt = 0; mt < 4; mt++)
#pragma unroll
        for (int r = 0; r < 4; r++) {
          float s = as[mt][nt][r];
          if (diag) {
            int key_g = kt * 64 + mt * 16 + quad * 4 + r;
            if (key_g > q_g) s = -1e30f;
          }
          sv[mt * 4 + r] = s;
        }
      float rm = sv[0];
#pragma unroll
      for (int i = 1; i < 16; i++) rm = fmaxf(rm, sv[i]);
      rm = fmaxf(rm, __shfl_xor(rm, 16));
      rm = fmaxf(rm, __shfl_xor(rm, 32));
      float mn = fmaxf(m_i[nt], rm);
      float alpha = fexp2(m_i[nt] - mn);
      m_i[nt] = mn;
      float rs = 0.f;
      float pv[16];
#pragma unroll
      for (int i = 0; i < 16; i++) {
        float p = fexp2(sv[i] - mn);
        pv[i] = p;
        rs += p;
      }
      rs += __shfl_xor(rs, 16);
      rs += __shfl_xor(rs, 32);
      l_i[nt] = l_i[nt] * alpha + rs;
#pragma unroll
      for (int mt = 0; mt < 4; mt++) ao[mt][nt] *= alpha;
#pragma unroll
      for (int mt = 0; mt < 4; mt++) {
        int pg = (2 * mt + (quad >> 1)) ^ (q_l & 7);
        int2 o;
        o.x = (int)pkbf16(pv[mt * 4 + 0], pv[mt * 4 + 1]);
        o.y = (int)pkbf16(pv[mt * 4 + 2], pv[mt * 4 + 3]);
        *(int2*)(Ps + q_l * 64 + pg * 8 + (quad & 1) * 4) = o;
      }
    }
    __syncthreads();

    // ---- O^T += V^T · P ----
    bfv8 pf[2][2];
#pragma unroll
    for (int nt = 0; nt < 2; nt++)
#pragma unroll
      for (int ks = 0; ks < 2; ks++) {
        int q_l = wave * 32 + nt * 16 + l15;
        int pg = (ks * 4 + quad) ^ (q_l & 7);
        pf[nt][ks] = *(const bfv8*)(Ps + q_l * 64 + pg * 8);
      }
#pragma unroll
    for (int mt = 0; mt < 4; mt++) {
      bfv8 va[2];
#pragma unroll
      for (int ks = 0; ks < 2; ks++) {
        int d = mt * 16 + l15;
        int pg = (ks * 4 + quad) ^ (d & 7);
        va[ks] = *(const bfv8*)(Vt + d * 64 + pg * 8);
      }
#pragma unroll
      for (int nt = 0; nt < 2; nt++)
#pragma unroll
        for (int ks = 0; ks < 2; ks++)
          ao[mt][nt] = __builtin_amdgcn_mfma_f32_16x16x32_bf16(
              va[ks], pf[nt][ks], ao[mt][nt], 0, 0, 0);
    }
  }

  // ---- epilogue: O^T -> LDS bounce (reuse Qs) -> coalesced Y stores ----
  __syncthreads();
#pragma unroll
  for (int nt = 0; nt < 2; nt++) {
    float inv = 1.0f / l_i[nt];
    int q_l = wave * 32 + nt * 16 + l15;
#pragma unroll
    for (int mt = 0; mt < 4; mt++) {
      int g = mt * 4 + quad;          // d-granule (4 elems)
      int gp = g ^ (q_l & 15);
      int2 o;
      o.x = (int)pkbf16(ao[mt][nt][0] * inv, ao[mt][nt][1] * inv);
      o.y = (int)pkbf16(ao[mt][nt][2] * inv, ao[mt][nt][3] * inv);
      *(int2*)(Qs + q_l * 64 + gp * 4) = o;
    }
  }
  __syncthreads();
#pragma unroll
  for (int rr = 0; rr < 4; rr++) {
    int q   = rr * 32 + (tid >> 3);
    int seg = tid & 7;
    int g0 = (2 * seg) ^ (q & 15), g1 = (2 * seg + 1) ^ (q & 15);
    int2 a  = *(const int2*)(Qs + q * 64 + g0 * 4);
    int2 bv = *(const int2*)(Qs + q * 64 + g1 * 4);
    int4 o; o.x = a.x; o.y = a.y; o.z = bv.x; o.w = bv.y;
    *(int4*)(Yg + ((size_t)b * T_SEQ + q0 + q) * C_DIM + h * HEAD_D + seg * 8) = o;
  }
}

extern "C" void kernel_launch(void* const* d_in, const int* in_sizes, int n_in,
                              void* d_out, int out_size, void* d_ws, size_t ws_size,
                              hipStream_t stream) {
  const float* x  = (const float*)d_in[0];
  const float* Wq = (const float*)d_in[1];
  const float* Wk = (const float*)d_in[2];
  const float* Wv = (const float*)d_in[3];
  const float* Wo = (const float*)d_in[4];
  float* out = (float*)d_out;

  const size_t NE = (size_t)B_SZ * T_SEQ * C_DIM;  // 8388608
  const size_t NW = (size_t)C_DIM * C_DIM;         // 1048576
  u16* xbf = (u16*)d_ws;
  u16* wqb = xbf + NE;   // 4 weight buffers contiguous (cvt_w relies on this)
  u16* wkb = wqb + NW;
  u16* wvb = wkb + NW;
  u16* wob = wvb + NW;
  u16* qws = wob + NW;
  u16* kws = qws + NE;
  u16* vws = kws + NE;   // V^T layout (B,H,D,T)
  u16* yws = vws + NE;

  cvt_kernel<<<(int)(NE / 4 / 256), 256, 0, stream>>>(x, xbf, (int)(NE / 4));
  cvt_w_kernel<<<dim3((int)(NW / 4 / 256), 4), 256, 0, stream>>>(Wq, Wk, Wv, Wo, wqb);

  dim3 g1(T_SEQ * B_SZ / 128, C_DIM / 128, 3);
  gemm_qkv_kernel<<<g1, 256, 0, stream>>>(xbf, wqb, wkb, wvb, qws, kws, vws);

  dim3 g2(B_SZ * N_HEAD, T_SEQ / ATT_Q);
  attn_kernel<<<g2, 256, 0, stream>>>(qws, kws, vws, yws);

  dim3 g3(T_SEQ * B_SZ / 128, C_DIM / 128);
  gemm_out_kernel<<<g3, 256, 0, stream>>>(yws, wob, out);
}

// Round 6
// 273.683 us; speedup vs baseline: 3.1327x; 1.0257x over previous
//
#include <hip/hip_runtime.h>
#include <stdint.h>

// Problem constants
#define B_SZ   4
#define T_SEQ  2048
#define C_DIM  1024
#define N_HEAD 16
#define HEAD_D 64
#define QSCALE 0.18033688011112042f  // (1/sqrt(64)) * log2(e): exp2-domain attn

typedef unsigned short u16;
typedef unsigned int   u32;
typedef __bf16  bfv8  __attribute__((ext_vector_type(8)));
typedef float   f32x4 __attribute__((ext_vector_type(4)));

__device__ __forceinline__ u16 f2bf_hu(float f) {  // round-half-up, 1-ulp
  union { float f; u32 i; } u; u.f = f;
  return (u16)((u.i + 0x8000u) >> 16);
}
__device__ __forceinline__ u32 pkbf16(float a, float b) {
  union { float f; u32 i; } ua, ub; ua.f = a; ub.f = b;
  return ((ua.i + 0x8000u) >> 16) | ((ub.i + 0x8000u) & 0xFFFF0000u);
}
__device__ __forceinline__ float fexp2(float x) {
#if __has_builtin(__builtin_amdgcn_exp2f)
  return __builtin_amdgcn_exp2f(x);
#else
  return __expf(x * 0.69314718f);
#endif
}
__device__ __forceinline__ void gload_lds16(const u16* g, u16* l) {
  __builtin_amdgcn_global_load_lds(
      (__attribute__((address_space(1))) void*)(void*)g,
      (__attribute__((address_space(3))) void*)(void*)l, 16, 0, 0);
}

// fp32 -> bf16 elementwise (x)
__global__ __launch_bounds__(256) void cvt_kernel(const float* __restrict__ src,
                                                  u16* __restrict__ dst, int n4) {
  int i = blockIdx.x * 256 + threadIdx.x;
  if (i < n4) {
    float4 v = ((const float4*)src)[i];
    int2 o; o.x = (int)pkbf16(v.x, v.y); o.y = (int)pkbf16(v.z, v.w);
    ((int2*)dst)[i] = o;
  }
}
__global__ __launch_bounds__(256) void cvt_w_kernel(
    const float* __restrict__ W0, const float* __restrict__ W1,
    const float* __restrict__ W2, const float* __restrict__ W3,
    u16* __restrict__ dst) {
  const float* s = (blockIdx.y == 0) ? W0 : (blockIdx.y == 1) ? W1
                 : (blockIdx.y == 2) ? W2 : W3;
  u16* d = dst + (size_t)blockIdx.y * (C_DIM * C_DIM);
  int i = blockIdx.x * 256 + threadIdx.x;
  float4 v = ((const float4*)s)[i];
  int2 o; o.x = (int)pkbf16(v.x, v.y); o.y = (int)pkbf16(v.z, v.w);
  ((int2*)d)[i] = o;
}

// ---------------------------------------------------------------------------
// NT GEMM core (r5-verified): 128x128 tile, BK=32, global_load_lds width=16.
// ---------------------------------------------------------------------------
__device__ __forceinline__ void gemm_core(const u16* __restrict__ A,
                                          const u16* __restrict__ Bw,
                                          int m0, int n0,
                                          f32x4 acc[4][4],
                                          u16* As, u16* Bs) {
  const int tid  = threadIdx.x;
  const int wave = tid >> 6;
  const int lane = tid & 63;
  const int lrow = lane >> 2;
  const int lcol = (lane & 3) * 8;
  const int frow = lane & 15;
  const int fk   = (lane >> 4) * 8;
  const int wm   = wave >> 1, wn = wave & 1;

  for (int k0 = 0; k0 < C_DIM; k0 += 32) {
    __syncthreads();
    const u16* ga = A + (size_t)(m0 + wave * 32 + lrow) * C_DIM + k0 + lcol;
    gload_lds16(ga,              As + (wave * 32) * 32);
    gload_lds16(ga + 16 * C_DIM, As + (wave * 32 + 16) * 32);
    const u16* gb = Bw + (size_t)(n0 + wave * 32 + lrow) * C_DIM + k0 + lcol;
    gload_lds16(gb,              Bs + (wave * 32) * 32);
    gload_lds16(gb + 16 * C_DIM, Bs + (wave * 32 + 16) * 32);
    __syncthreads();

    bfv8 af[4], bfr[4];
#pragma unroll
    for (int mt = 0; mt < 4; mt++)
      af[mt] = *(const bfv8*)(As + (wm * 64 + mt * 16 + frow) * 32 + fk);
#pragma unroll
    for (int nt = 0; nt < 4; nt++)
      bfr[nt] = *(const bfv8*)(Bs + (wn * 64 + nt * 16 + frow) * 32 + fk);
#pragma unroll
    for (int mt = 0; mt < 4; mt++)
#pragma unroll
      for (int nt = 0; nt < 4; nt++)
        acc[mt][nt] = __builtin_amdgcn_mfma_f32_16x16x32_bf16(
            af[mt], bfr[nt], acc[mt][nt], 0, 0, 0);
  }
}

// QKV projections. Q (pre-scaled by QSCALE), K -> (B,H,T,D); V -> (B,H,D,T).
// ALL epilogues via wave-private LDS bounce -> contiguous 128B global stores.
__global__ __launch_bounds__(256) void gemm_qkv_kernel(
    const u16* __restrict__ X, const u16* __restrict__ Wq,
    const u16* __restrict__ Wk, const u16* __restrict__ Wv,
    u16* __restrict__ Qo, u16* __restrict__ Ko, u16* __restrict__ Vo) {
  __shared__ __align__(16) u16 smem[16384];  // 32 KB: As|Bs, then bounce
  u16* As = smem; u16* Bs = smem + 4096;
  const u16* W = (blockIdx.z == 0) ? Wq : (blockIdx.z == 1) ? Wk : Wv;
  u16* dst     = (blockIdx.z == 0) ? Qo : (blockIdx.z == 1) ? Ko : Vo;
  const int m0 = blockIdx.x * 128, n0 = blockIdx.y * 128;

  f32x4 acc[4][4];
#pragma unroll
  for (int i = 0; i < 4; i++)
#pragma unroll
    for (int j = 0; j < 4; j++) acc[i][j] = {0.f, 0.f, 0.f, 0.f};

  gemm_core(X, W, m0, n0, acc, As, Bs);
  __syncthreads();  // fragment reads done; smem reusable

  const int lane = threadIdx.x & 63, wave = threadIdx.x >> 6;
  const int wm = wave >> 1, wn = wave & 1;
  const int quad = lane >> 4, col = lane & 15;
  u16* buf = smem + wave * 4096;             // 8 KB wave-private
  const int bb = (m0 + wm * 64) >> 11;
  const int t0 = (m0 + wm * 64) & (T_SEQ - 1);
  const int h  = (n0 >> 6) + wn;

  if (blockIdx.z == 2) {
    // ---- V^T: buf[d 0..63][t granules of 4], int2-packed (r over t) ----
#pragma unroll
    for (int mt = 0; mt < 4; mt++)
#pragma unroll
      for (int nt = 0; nt < 4; nt++) {
        int d_l = nt * 16 + col;
        int g   = mt * 4 + quad;
        int gp  = g ^ (d_l & 15);
        int2 o;
        o.x = (int)pkbf16(acc[mt][nt][0], acc[mt][nt][1]);
        o.y = (int)pkbf16(acc[mt][nt][2], acc[mt][nt][3]);
        *(int2*)(buf + d_l * 64 + gp * 4) = o;
      }
#pragma unroll
    for (int tt = 0; tt < 8; tt++) {
      int d_l = tt * 8 + (lane >> 3);
      int seg = lane & 7;
      int g0 = (2 * seg) ^ (d_l & 15), g1 = (2 * seg + 1) ^ (d_l & 15);
      int2 a  = *(const int2*)(buf + d_l * 64 + g0 * 4);
      int2 bv = *(const int2*)(buf + d_l * 64 + g1 * 4);
      int4 o; o.x = a.x; o.y = a.y; o.z = bv.x; o.w = bv.y;
      *(int4*)(Vo + (((size_t)(bb * N_HEAD + h) * HEAD_D + d_l) * T_SEQ
                     + t0 + seg * 8)) = o;
    }
  } else {
    // ---- Q/K: buf[m 0..63][n 0..63], scalar writes + 8-granule swizzle ----
    const float sc = (blockIdx.z == 0) ? QSCALE : 1.0f;
#pragma unroll
    for (int mt = 0; mt < 4; mt++)
#pragma unroll
      for (int nt = 0; nt < 4; nt++)
#pragma unroll
        for (int r = 0; r < 4; r++) {
          int m_l = mt * 16 + quad * 4 + r;
          int n_l = nt * 16 + col;
          int gp = (n_l >> 3) ^ (m_l & 7);
          buf[m_l * 64 + gp * 8 + (n_l & 7)] = f2bf_hu(acc[mt][nt][r] * sc);
        }
#pragma unroll
    for (int tt = 0; tt < 8; tt++) {
      int m_l = tt * 8 + (lane >> 3);
      int seg = lane & 7;
      int gp = seg ^ (m_l & 7);
      int4 o = *(const int4*)(buf + m_l * 64 + gp * 8);
      *(int4*)(dst + (((size_t)(bb * N_HEAD + h) * T_SEQ + t0 + m_l) * HEAD_D
                      + seg * 8)) = o;
    }
  }
}

// Output projection: (B,T,C) fp32, epilogue via wave-private f32 bounce.
__global__ __launch_bounds__(256) void gemm_out_kernel(
    const u16* __restrict__ Y, const u16* __restrict__ Wo,
    float* __restrict__ Out) {
  __shared__ __align__(16) u16 smem[16384];  // 32 KB
  u16* As = smem; u16* Bs = smem + 4096;
  const int m0 = blockIdx.x * 128, n0 = blockIdx.y * 128;

  f32x4 acc[4][4];
#pragma unroll
  for (int i = 0; i < 4; i++)
#pragma unroll
    for (int j = 0; j < 4; j++) acc[i][j] = {0.f, 0.f, 0.f, 0.f};

  gemm_core(Y, Wo, m0, n0, acc, As, Bs);
  __syncthreads();

  const int lane = threadIdx.x & 63, wave = threadIdx.x >> 6;
  const int wm = wave >> 1, wn = wave & 1;
  const int quad = lane >> 4, col = lane & 15;
  float* bufF = (float*)(smem + wave * 4096);  // 2048 floats wave-private

#pragma unroll
  for (int c = 0; c < 2; c++) {
#pragma unroll
    for (int mt = 0; mt < 4; mt++)
#pragma unroll
      for (int nn = 0; nn < 2; nn++)
#pragma unroll
        for (int r = 0; r < 4; r++) {
          int nt = 2 * c + nn;
          int m_l = mt * 16 + quad * 4 + r;
          int n_l = nn * 16 + col;
          int gp = (n_l >> 2) ^ (m_l & 7);
          bufF[m_l * 32 + gp * 4 + (n_l & 3)] = acc[mt][nt][r];
        }
#pragma unroll
    for (int tt = 0; tt < 8; tt++) {
      int m_l = tt * 8 + (lane >> 3);
      int seg = lane & 7;
      int gp = seg ^ (m_l & 7);
      float4 o = *(const float4*)(bufF + m_l * 32 + gp * 4);
      *(float4*)(Out + (size_t)(m0 + wm * 64 + m_l) * C_DIM
                 + n0 + wn * 64 + c * 32 + seg * 4) = o;
    }
  }
}

// ---------------------------------------------------------------------------
// MFMA flash attention (causal), exp2 domain. Block = (b,h) x 128-q tile;
// 4 waves x 32 q; 64-key tiles with REGISTER-PREFETCHED K/V staging.
// LDS 32 KB (Ps overlaid on Qs) -> 4-5 blocks/CU, whole grid co-resident.
// ---------------------------------------------------------------------------
#define ATT_Q 128

__global__ __launch_bounds__(256, 4) void attn_kernel(
    const u16* __restrict__ Qg, const u16* __restrict__ Kg,
    const u16* __restrict__ Vtg, u16* __restrict__ Yg) {
  __shared__ __align__(16) u16 QPs[128 * 64];  // Q staging, then P^T, then Y-bounce
  __shared__ __align__(16) u16 Ks[64 * 64];
  __shared__ __align__(16) u16 Vt[64 * 64];

  const int tid = threadIdx.x;
  const int wave = tid >> 6, lane = tid & 63;
  const int quad = lane >> 4, l15 = lane & 15;
  const int bh = blockIdx.x;
  const int b = bh >> 4, h = bh & 15;
  // balanced qt map: each CU's 4 resident blocks sum to equal work
  const int yy = blockIdx.y, gq = yy >> 2, rq = yy & 3;
  const int qt = (gq == 0) ? 15 - rq : (gq == 1) ? rq
               : (gq == 2) ? 11 - rq : 4 + rq;
  const int q0 = qt * ATT_Q;

  // ---- stage Q tile (already exp2-prescaled by projection) ----
  {
    const int row = tid >> 1;
    const int c0 = (tid & 1) * 32;
    const u16* gp = Qg + ((size_t)bh * T_SEQ + q0 + row) * HEAD_D + c0;
#pragma unroll
    for (int g = 0; g < 4; g++) {
      int4 v = *(const int4*)(gp + g * 8);
      int pg = ((c0 >> 3) + g) ^ (row & 7);
      *(int4*)(QPs + row * 64 + pg * 8) = v;
    }
  }
  __syncthreads();

  bfv8 qb[2][2];
#pragma unroll
  for (int nt = 0; nt < 2; nt++)
#pragma unroll
    for (int ks = 0; ks < 2; ks++) {
      int q = wave * 32 + nt * 16 + l15;
      int pg = (ks * 4 + quad) ^ (q & 7);
      qb[nt][ks] = *(const bfv8*)(QPs + q * 64 + pg * 8);
    }

  float m_i[2] = {-1e30f, -1e30f}, l_i[2] = {0.f, 0.f};
  f32x4 ao[4][2];
#pragma unroll
  for (int mt = 0; mt < 4; mt++)
#pragma unroll
    for (int nt = 0; nt < 2; nt++) ao[mt][nt] = {0.f, 0.f, 0.f, 0.f};

  // prefetch pointers (per-thread staging slice)
  const int srow = tid >> 2;
  const int sc0 = (tid & 3) * 16;
  const u16* gkb = Kg  + (size_t)bh * T_SEQ * HEAD_D + (size_t)srow * HEAD_D + sc0;
  const u16* gvb = Vtg + (size_t)bh * HEAD_D * T_SEQ + (size_t)srow * T_SEQ + sc0;
  const int pg0 = (sc0 >> 3) ^ (srow & 7), pg1 = ((sc0 >> 3) + 1) ^ (srow & 7);

  int4 kr0, kr1, vr0, vr1;
  kr0 = *(const int4*)(gkb);      kr1 = *(const int4*)(gkb + 8);
  vr0 = *(const int4*)(gvb);      vr1 = *(const int4*)(gvb + 8);

  const int ktmax = 2 * qt + 1;
  for (int kt = 0; kt <= ktmax; kt++) {
    __syncthreads();  // prev iter done reading Ks/Vt
    *(int4*)(Ks + srow * 64 + pg0 * 8) = kr0;
    *(int4*)(Ks + srow * 64 + pg1 * 8) = kr1;
    *(int4*)(Vt + srow * 64 + pg0 * 8) = vr0;
    *(int4*)(Vt + srow * 64 + pg1 * 8) = vr1;
    __syncthreads();
    if (kt < ktmax) {  // prefetch next tile; waited next iteration
      const u16* gk = gkb + (size_t)(kt + 1) * 64 * HEAD_D;
      const u16* gv = gvb + (kt + 1) * 64;
      kr0 = *(const int4*)(gk);  kr1 = *(const int4*)(gk + 8);
      vr0 = *(const int4*)(gv);  vr1 = *(const int4*)(gv + 8);
    }

    // ---- S^T = K · Q^T ----
    f32x4 as[4][2];
#pragma unroll
    for (int mt = 0; mt < 4; mt++)
#pragma unroll
      for (int nt = 0; nt < 2; nt++) as[mt][nt] = {0.f, 0.f, 0.f, 0.f};
#pragma unroll
    for (int mt = 0; mt < 4; mt++) {
      bfv8 ka[2];
#pragma unroll
      for (int ks = 0; ks < 2; ks++) {
        int key = mt * 16 + l15;
        int pg = (ks * 4 + quad) ^ (key & 7);
        ka[ks] = *(const bfv8*)(Ks + key * 64 + pg * 8);
      }
#pragma unroll
      for (int nt = 0; nt < 2; nt++)
#pragma unroll
        for (int ks = 0; ks < 2; ks++)
          as[mt][nt] = __builtin_amdgcn_mfma_f32_16x16x32_bf16(
              ka[ks], qb[nt][ks], as[mt][nt], 0, 0, 0);
    }

    // ---- online softmax (exp2 domain) ----
    const bool diag = (kt >= 2 * qt);
#pragma unroll
    for (int nt = 0; nt < 2; nt++) {
      const int q_l = wave * 32 + nt * 16 + l15;
      const int q_g = q0 + q_l;
      float sv[16];
#pragma unroll
      for (int mt = 0; mt < 4; mt++)
#pragma unroll
        for (int r = 0; r < 4; r++) {
          float s = as[mt][nt][r];
          if (diag) {
            int key_g = kt * 64 + mt * 16 + quad * 4 + r;
            if (key_g > q_g) s = -1e30f;
          }
          sv[mt * 4 + r] = s;
        }
      float rm = sv[0];
#pragma unroll
      for (int i = 1; i < 16; i++) rm = fmaxf(rm, sv[i]);
      rm = fmaxf(rm, __shfl_xor(rm, 16));
      rm = fmaxf(rm, __shfl_xor(rm, 32));
      float mn = fmaxf(m_i[nt], rm);
      float alpha = fexp2(m_i[nt] - mn);
      m_i[nt] = mn;
      float rs = 0.f;
      float pv[16];
#pragma unroll
      for (int i = 0; i < 16; i++) {
        float p = fexp2(sv[i] - mn);
        pv[i] = p;
        rs += p;
      }
      rs += __shfl_xor(rs, 16);
      rs += __shfl_xor(rs, 32);
      l_i[nt] = l_i[nt] * alpha + rs;
#pragma unroll
      for (int mt = 0; mt < 4; mt++) ao[mt][nt] *= alpha;
      // P^T -> QPs[q][key] (wave-private rows; no barrier needed)
#pragma unroll
      for (int mt = 0; mt < 4; mt++) {
        int pg = (2 * mt + (quad >> 1)) ^ (q_l & 7);
        int2 o;
        o.x = (int)pkbf16(pv[mt * 4 + 0], pv[mt * 4 + 1]);
        o.y = (int)pkbf16(pv[mt * 4 + 2], pv[mt * 4 + 3]);
        *(int2*)(QPs + q_l * 64 + pg * 8 + (quad & 1) * 4) = o;
      }
    }

    // ---- O^T += V^T · P (P rows are same-wave; LDS order via lgkmcnt) ----
    bfv8 pf[2][2];
#pragma unroll
    for (int nt = 0; nt < 2; nt++)
#pragma unroll
      for (int ks = 0; ks < 2; ks++) {
        int q_l = wave * 32 + nt * 16 + l15;
        int pg = (ks * 4 + quad) ^ (q_l & 7);
        pf[nt][ks] = *(const bfv8*)(QPs + q_l * 64 + pg * 8);
      }
#pragma unroll
    for (int mt = 0; mt < 4; mt++) {
      bfv8 va[2];
#pragma unroll
      for (int ks = 0; ks < 2; ks++) {
        int d = mt * 16 + l15;
        int pg = (ks * 4 + quad) ^ (d & 7);
        va[ks] = *(const bfv8*)(Vt + d * 64 + pg * 8);
      }
#pragma unroll
      for (int nt = 0; nt < 2; nt++)
#pragma unroll
        for (int ks = 0; ks < 2; ks++)
          ao[mt][nt] = __builtin_amdgcn_mfma_f32_16x16x32_bf16(
              va[ks], pf[nt][ks], ao[mt][nt], 0, 0, 0);
    }
  }

  // ---- epilogue: O^T -> LDS bounce (QPs) -> coalesced Y stores ----
  __syncthreads();
#pragma unroll
  for (int nt = 0; nt < 2; nt++) {
    float inv = 1.0f / l_i[nt];
    int q_l = wave * 32 + nt * 16 + l15;
#pragma unroll
    for (int mt = 0; mt < 4; mt++) {
      int g = mt * 4 + quad;
      int gp = g ^ (q_l & 15);
      int2 o;
      o.x = (int)pkbf16(ao[mt][nt][0] * inv, ao[mt][nt][1] * inv);
      o.y = (int)pkbf16(ao[mt][nt][2] * inv, ao[mt][nt][3] * inv);
      *(int2*)(QPs + q_l * 64 + gp * 4) = o;
    }
  }
  __syncthreads();
#pragma unroll
  for (int rr = 0; rr < 4; rr++) {
    int q   = rr * 32 + (tid >> 3);
    int seg = tid & 7;
    int g0 = (2 * seg) ^ (q & 15), g1 = (2 * seg + 1) ^ (q & 15);
    int2 a  = *(const int2*)(QPs + q * 64 + g0 * 4);
    int2 bv = *(const int2*)(QPs + q * 64 + g1 * 4);
    int4 o; o.x = a.x; o.y = a.y; o.z = bv.x; o.w = bv.y;
    *(int4*)(Yg + ((size_t)b * T_SEQ + q0 + q) * C_DIM + h * HEAD_D + seg * 8) = o;
  }
}

extern "C" void kernel_launch(void* const* d_in, const int* in_sizes, int n_in,
                              void* d_out, int out_size, void* d_ws, size_t ws_size,
                              hipStream_t stream) {
  const float* x  = (const float*)d_in[0];
  const float* Wq = (const float*)d_in[1];
  const float* Wk = (const float*)d_in[2];
  const float* Wv = (const float*)d_in[3];
  const float* Wo = (const float*)d_in[4];
  float* out = (float*)d_out;

  const size_t NE = (size_t)B_SZ * T_SEQ * C_DIM;  // 8388608
  const size_t NW = (size_t)C_DIM * C_DIM;         // 1048576
  u16* xbf = (u16*)d_ws;
  u16* wqb = xbf + NE;   // 4 weight buffers contiguous
  u16* wkb = wqb + NW;
  u16* wvb = wkb + NW;
  u16* wob = wvb + NW;
  u16* qws = wob + NW;
  u16* kws = qws + NE;
  u16* vws = kws + NE;   // V^T layout (B,H,D,T)
  u16* yws = vws + NE;

  cvt_kernel<<<(int)(NE / 4 / 256), 256, 0, stream>>>(x, xbf, (int)(NE / 4));
  cvt_w_kernel<<<dim3((int)(NW / 4 / 256), 4), 256, 0, stream>>>(Wq, Wk, Wv, Wo, wqb);

  dim3 g1(T_SEQ * B_SZ / 128, C_DIM / 128, 3);
  gemm_qkv_kernel<<<g1, 256, 0, stream>>>(xbf, wqb, wkb, wvb, qws, kws, vws);

  dim3 g2(B_SZ * N_HEAD, T_SEQ / ATT_Q);
  attn_kernel<<<g2, 256, 0, stream>>>(qws, kws, vws, yws);

  dim3 g3(T_SEQ * B_SZ / 128, C_DIM / 128);
  gemm_out_kernel<<<g3, 256, 0, stream>>>(yws, wob, out);
}